// Round 7
// baseline (287.169 us; speedup 1.0000x reference)
//
#include <hip/hip_runtime.h>

// Problem constants
#define BATCH   4096
#define NF      39          // num_field
#define ED      16          // embedding size
#define IN_DIM  624         // NF*ED
#define DW      400
#define BN_EPS  1e-5f
#define NKSG    80          // CIN K-steps: 40 m-slots (m=39 zero-padded) * 2
#define AK1     640         // padded deep K for layer 1 input (624 -> 640)
#define NKS1    20          // AK1/32
#define NKS2    13          // 400 -> 416 padded
#define WCOL    416         // padded deep-weight column count

typedef __attribute__((ext_vector_type(8))) short short8;
typedef __attribute__((ext_vector_type(4))) float f32x4;
typedef unsigned short u16;

__device__ inline unsigned pack_hi2(float a, float b) {
  // [a>>16 | b&0xffff0000] in one v_perm_b32
  return __builtin_amdgcn_perm(__float_as_uint(b), __float_as_uint(a), 0x07060302u);
}
__device__ inline unsigned bf16_rne(float f) {
  unsigned u = __float_as_uint(f);
  u += 0x7fff + ((u >> 16) & 1);
  return u >> 16;
}
__device__ inline float bf2f(u16 v) { return __uint_as_float((unsigned)v << 16); }

#define CIN_E (NKSG * 128 * 32)      // 327680
#define D1_E  (NKS1 * WCOL * 32)     // 266240
#define D2_E  (NKS2 * WCOL * 32)     // 173056
#define PREP_E (CIN_E + D1_E + D2_E + 1600)
#define PREP_B ((PREP_E + 255) / 256)

// ---------------------------------------------------------------------------
// Merged: blocks < BATCH gather embeddings (+linear part); rest pack weights
// into B-fragment layout and zero BN-stat accumulators.
// ---------------------------------------------------------------------------
__global__ __launch_bounds__(256) void k_gp(const int* __restrict__ idx,
    const float* __restrict__ emb, const float* __restrict__ lw,
    const float* __restrict__ lb, const float* __restrict__ w1,
    const float* __restrict__ w2, const float* __restrict__ dw1,
    const float* __restrict__ dw2, u16* __restrict__ flatb,
    float* __restrict__ lp, u16* __restrict__ wp1, u16* __restrict__ wp2,
    u16* __restrict__ wpd1, u16* __restrict__ wpd2, float* __restrict__ gstat) {
  int t = threadIdx.x;
  if (blockIdx.x < BATCH) {
    int b = blockIdx.x;
    __shared__ int si[NF];
    __shared__ float r4[4];
    if (t < NF) si[t] = idx[b * NF + t];
    __syncthreads();
    float acc = 0.f;
#pragma unroll
    for (int i = 0; i < 3; i++) {
      int e = t + i * 256;
      if (e < IN_DIM) {
        float v = emb[(size_t)si[e >> 4] * ED + (e & 15)];
        flatb[(size_t)b * AK1 + e] = (u16)bf16_rne(v);
        acc = fmaf(v, lw[e], acc);
      } else if (e < AK1) {
        flatb[(size_t)b * AK1 + e] = 0;
      }
    }
#pragma unroll
    for (int k = 1; k < 64; k <<= 1) acc += __shfl_xor(acc, k);
    if ((t & 63) == 0) r4[t >> 6] = acc;
    __syncthreads();
    if (t == 0) lp[b] = r4[0] + r4[1] + r4[2] + r4[3] + lb[0];
  } else {
    int e = (blockIdx.x - BATCH) * 256 + t;
    if (e < CIN_E) {
      int ksg = e >> 12, r = e & 4095, n = r >> 5, kk = r & 31;
      int k = ksg * 32 + kk, h = k & 63, m = k >> 6;   // m in [0,40)
      float v1 = (h < NF && m < NF) ? w1[(size_t)n * (NF * NF) + h * NF + m] : 0.f;
      float v2 = (m < NF) ? w2[(size_t)n * (64 * NF) + h * NF + m] : 0.f;
      wp1[e] = (u16)bf16_rne(v1);
      wp2[e] = (u16)bf16_rne(v2);
    } else if (e < CIN_E + D1_E) {
      int e2 = e - CIN_E;
      int ksg = e2 / (WCOL * 32), r = e2 - ksg * (WCOL * 32);
      int col = r >> 5, kk = r & 31;
      int k = ksg * 32 + kk;
      wpd1[e2] = (k < IN_DIM && col < DW) ? (u16)bf16_rne(dw1[(size_t)k * DW + col]) : 0;
    } else if (e < CIN_E + D1_E + D2_E) {
      int e2 = e - CIN_E - D1_E;
      int ksg = e2 / (WCOL * 32), r = e2 - ksg * (WCOL * 32);
      int col = r >> 5, kk = r & 31;
      int k = ksg * 32 + kk;
      wpd2[e2] = (k < DW && col < DW) ? (u16)bf16_rne(dw2[(size_t)k * DW + col]) : 0;
    } else if (e < PREP_E) {
      gstat[e - CIN_E - D1_E - D2_E] = 0.f;
    }
  }
}

// ---------------------------------------------------------------------------
// CIN via MFMA. N-split x2 (grid.y) AND in-block K-split x2 (wave pairs).
// Grid (BATCH/8, 2) = 1024 blocks -> 4 blocks/CU -> 4 waves/SIMD.
// Block = 4 waves = 2 sample-pairs x 2 K-halves (m in [0,20) / [20,40);
// m=39 is zero-padded so both halves run a compile-time 20-trip loop).
// Half-1 partials reduced through 32 KB LDS; half-0 runs the epilogue.
// B-frags double-buffered from L2; A built in-register with v_perm packs.
// ---------------------------------------------------------------------------
template <bool LAY2>
__global__ __launch_bounds__(256, 2) void k_cin_mfma(
    const u16* __restrict__ flatb, const u16* __restrict__ nxtg,
    const u16* __restrict__ wp, const float* __restrict__ bias,
    u16* __restrict__ nxt_out, float* __restrict__ res) {
  __shared__ f32x4 lds4[2 * 16 * 64];    // 32 KB
  int t = threadIdx.x;
  int w = t >> 6, lane = t & 63;
  int pair = w >> 1, half = w & 1;
  int nl = lane & 15, q = lane >> 4;
  int d = nl;
  int b0 = blockIdx.x * 8 + pair * 4;
  int c0 = blockIdx.y * 64;
  int M0 = half * 20;

  // s1 regs: nxr[si][ks][w4] = packed bf16 pair, h = ks*32+q*8+2*w4(+1)
  unsigned nxr[4][2][4];
  if (LAY2) {
#pragma unroll
    for (int si = 0; si < 4; si++)
#pragma unroll
      for (int ks = 0; ks < 2; ks++) {
        uint4 v = *(const uint4*)(nxtg +
            (((size_t)(b0 + si) * 16 + d) * 64 + ks * 32 + q * 8));
        nxr[si][ks][0] = v.x; nxr[si][ks][1] = v.y;
        nxr[si][ks][2] = v.z; nxr[si][ks][3] = v.w;
      }
  } else {
#pragma unroll
    for (int si = 0; si < 4; si++)
#pragma unroll
      for (int ks = 0; ks < 2; ks++)
#pragma unroll
        for (int w4 = 0; w4 < 4; w4++) {
          int h0 = ks * 32 + q * 8 + 2 * w4;
          int h1 = h0 + 1;
          unsigned u0 = (h0 < NF) ? flatb[(size_t)(b0 + si) * AK1 + h0 * 16 + d] : 0;
          unsigned u1 = (h1 < NF) ? flatb[(size_t)(b0 + si) * AK1 + h1 * 16 + d] : 0;
          nxr[si][ks][w4] = u0 | (u1 << 16);
        }
  }

  f32x4 acc[4][4];
#pragma unroll
  for (int si = 0; si < 4; si++)
#pragma unroll
    for (int nt = 0; nt < 4; nt++) acc[si][nt] = (f32x4){0.f, 0.f, 0.f, 0.f};

  const u16* wbase = wp + (size_t)(c0 + nl) * 32 + q * 8;
  short8 bfr[2][4];
#pragma unroll
  for (int nt = 0; nt < 4; nt++)
    bfr[0][nt] = *(const short8*)(wbase + (size_t)(M0 * 2) * 4096 + nt * 512);

  float xv[4], xvn[4];
#pragma unroll
  for (int si = 0; si < 4; si++)
    xv[si] = bf2f(flatb[(size_t)(b0 + si) * AK1 + M0 * 16 + d]);

#pragma unroll 2
  for (int i = 0; i < 20; i++) {
    int m = M0 + i;
    if (i + 1 < 20) {
#pragma unroll
      for (int si = 0; si < 4; si++)
        xvn[si] = bf2f(flatb[(size_t)(b0 + si) * AK1 + (m + 1) * 16 + d]);
    }
#pragma unroll
    for (int ks = 0; ks < 2; ks++) {
      int nx = ks ^ 1;
      int nksg = m * 2 + ks + 1;               // next K-step
      if (ks == 0 || i + 1 < 20) {
        const u16* wb = wbase + (size_t)nksg * 4096;
#pragma unroll
        for (int nt = 0; nt < 4; nt++)
          bfr[nx][nt] = *(const short8*)(wb + nt * 512);
      }
      short8 afr[4];
#pragma unroll
      for (int si = 0; si < 4; si++) {
        union { unsigned u[4]; short8 s; } a;
#pragma unroll
        for (int w4 = 0; w4 < 4; w4++) {
          unsigned u = nxr[si][ks][w4];
          float lo = __uint_as_float(u << 16) * xv[si];
          float hi = __uint_as_float(u & 0xffff0000u) * xv[si];
          a.u[w4] = pack_hi2(lo, hi);
        }
        afr[si] = a.s;
      }
#pragma unroll
      for (int nt = 0; nt < 4; nt++)
#pragma unroll
        for (int si = 0; si < 4; si++)
          acc[si][nt] = __builtin_amdgcn_mfma_f32_16x16x32_bf16(
              afr[si], bfr[ks][nt], acc[si][nt], 0, 0, 0);
    }
#pragma unroll
    for (int si = 0; si < 4; si++) xv[si] = xvn[si];
  }

  // K-split reduction: half 1 dumps partials to LDS, half 0 adds + epilogue.
  if (half) {
#pragma unroll
    for (int si = 0; si < 4; si++)
#pragma unroll
      for (int nt = 0; nt < 4; nt++)
        lds4[(pair * 16 + si * 4 + nt) * 64 + lane] = acc[si][nt];
  }
  __syncthreads();
  if (half) return;
#pragma unroll
  for (int si = 0; si < 4; si++)
#pragma unroll
    for (int nt = 0; nt < 4; nt++) {
      f32x4 p = lds4[(pair * 16 + si * 4 + nt) * 64 + lane];
      acc[si][nt][0] += p[0]; acc[si][nt][1] += p[1];
      acc[si][nt][2] += p[2]; acc[si][nt][3] += p[3];
    }

  // Epilogue. C layout: col = nl (within n-tile), row d' = q*4 + r.
#pragma unroll
  for (int si = 0; si < 4; si++) {
    int b = b0 + si;
#pragma unroll
    for (int nt = 0; nt < 4; nt++) {
      int o = c0 + nt * 16 + nl;
      float bi = bias[o];
      if (!LAY2 && c0 == 0) {
#pragma unroll
        for (int r = 0; r < 4; r++) {
          float v = fmaxf(acc[si][nt][r] + bi, 0.f);
          nxt_out[((size_t)b * 16 + q * 4 + r) * 64 + o] = (u16)bf16_rne(v);
        }
      } else {
        float s = 0.f;
#pragma unroll
        for (int r = 0; r < 4; r++) s += fmaxf(acc[si][nt][r] + bi, 0.f);
        s += __shfl_xor(s, 16);
        s += __shfl_xor(s, 32);
        if (q == 0) {
          int ri = LAY2 ? (64 + o) : (o - 64);
          res[(size_t)b * 192 + ri] = s;
        }
      }
    }
  }
}

// ---------------------------------------------------------------------------
// Deep-tower GEMM via MFMA. Grid (M/64, 13), wave = 16 rows x 32 cols
// (2 n-tiles) -> A-replication x13. Weights padded to 416 cols.
// BN_A folds previous layer's BN finalize in-block and applies BN+ReLU to A.
// Fused BN stats of C -> global atomics.
// ---------------------------------------------------------------------------
template <bool BN_A, int NKS, int KREAL, int AK>
__global__ __launch_bounds__(256) void k_gemm_mfma(
    const u16* __restrict__ Abf, const float* __restrict__ Af32,
    const u16* __restrict__ wp, const float* __restrict__ bias,
    const float* __restrict__ gsIn, const float* __restrict__ gs2In,
    const float* __restrict__ bng, const float* __restrict__ bnb,
    float* __restrict__ C, float* __restrict__ gs, float* __restrict__ gs2) {
  __shared__ float lsS[NKS * 32], lsH[NKS * 32];
  __shared__ float lred[64];
  int t = threadIdx.x;
  if (BN_A) {
    for (int c = t; c < NKS * 32; c += 256) {
      float sc = 0.f, sh = 0.f;
      if (c < DW) {
        float m = gsIn[c] * (1.f / BATCH);
        float var = gs2In[c] * (1.f / BATCH) - m * m;
        sc = bng[c] * rsqrtf(var + BN_EPS);
        sh = bnb[c] - m * sc;
      }
      lsS[c] = sc; lsH[c] = sh;
    }
  }
  if (t < 64) lred[t] = 0.f;
  __syncthreads();

  int w = t >> 6, lane = t & 63;
  int nl = lane & 15, q = lane >> 4;
  int row = blockIdx.x * 64 + w * 16 + nl;
  int c0 = blockIdx.y * 32;
  f32x4 acc[2];
  acc[0] = (f32x4){0.f, 0.f, 0.f, 0.f};
  acc[1] = (f32x4){0.f, 0.f, 0.f, 0.f};

  short8 araw[2]; f32x4 fraw0[2], fraw1[2]; short8 braw[2][2];
  auto loadA_raw = [&](int ksg, int buf) {
    int kb = ksg * 32 + q * 8;
    if (!BN_A) {
      araw[buf] = *(const short8*)(Abf + (size_t)row * AK + kb);
    } else {
      if (kb + 8 <= KREAL) {
        fraw0[buf] = *(const f32x4*)(Af32 + (size_t)row * KREAL + kb);
        fraw1[buf] = *(const f32x4*)(Af32 + (size_t)row * KREAL + kb + 4);
      } else {
        fraw0[buf] = (f32x4){0.f,0.f,0.f,0.f};
        fraw1[buf] = (f32x4){0.f,0.f,0.f,0.f};
      }
    }
    const u16* wb = wp + (size_t)ksg * (WCOL * 32) + (size_t)(c0 + nl) * 32 + q * 8;
    braw[buf][0] = *(const short8*)wb;
    braw[buf][1] = *(const short8*)(wb + 16 * 32);
  };
  auto cookA = [&](int ksg, int buf) -> short8 {
    if (!BN_A) return araw[buf];
    int kb = ksg * 32 + q * 8;
    f32x4 s0 = *(const f32x4*)&lsS[kb], h0 = *(const f32x4*)&lsH[kb];
    f32x4 s1 = *(const f32x4*)&lsS[kb + 4], h1 = *(const f32x4*)&lsH[kb + 4];
    union { unsigned u[4]; short8 s; } a;
    float v0 = fmaxf(fmaf(fraw0[buf][0], s0[0], h0[0]), 0.f);
    float v1 = fmaxf(fmaf(fraw0[buf][1], s0[1], h0[1]), 0.f);
    float v2 = fmaxf(fmaf(fraw0[buf][2], s0[2], h0[2]), 0.f);
    float v3 = fmaxf(fmaf(fraw0[buf][3], s0[3], h0[3]), 0.f);
    float v4 = fmaxf(fmaf(fraw1[buf][0], s1[0], h1[0]), 0.f);
    float v5 = fmaxf(fmaf(fraw1[buf][1], s1[1], h1[1]), 0.f);
    float v6 = fmaxf(fmaf(fraw1[buf][2], s1[2], h1[2]), 0.f);
    float v7 = fmaxf(fmaf(fraw1[buf][3], s1[3], h1[3]), 0.f);
    a.u[0] = bf16_rne(v0) | (bf16_rne(v1) << 16);
    a.u[1] = bf16_rne(v2) | (bf16_rne(v3) << 16);
    a.u[2] = bf16_rne(v4) | (bf16_rne(v5) << 16);
    a.u[3] = bf16_rne(v6) | (bf16_rne(v7) << 16);
    return a.s;
  };

  loadA_raw(0, 0);
#pragma unroll 4
  for (int ksg = 0; ksg < NKS; ksg++) {
    int cur = ksg & 1;
    if (ksg + 1 < NKS) loadA_raw(ksg + 1, cur ^ 1);
    short8 afr = cookA(ksg, cur);
    acc[0] = __builtin_amdgcn_mfma_f32_16x16x32_bf16(afr, braw[cur][0], acc[0], 0, 0, 0);
    acc[1] = __builtin_amdgcn_mfma_f32_16x16x32_bf16(afr, braw[cur][1], acc[1], 0, 0, 0);
  }

  int rbase = blockIdx.x * 64 + w * 16 + q * 4;
#pragma unroll
  for (int nt = 0; nt < 2; nt++) {
    int col = c0 + nt * 16 + nl;
    if (col < DW) {
      float bi = bias[col];
      float s = 0.f, s2 = 0.f;
#pragma unroll
      for (int r = 0; r < 4; r++) {
        float v = acc[nt][r] + bi;
        C[(size_t)(rbase + r) * DW + col] = v;
        s += v; s2 = fmaf(v, v, s2);
      }
      s += __shfl_xor(s, 16); s2 += __shfl_xor(s2, 16);
      s += __shfl_xor(s, 32); s2 += __shfl_xor(s2, 32);
      if (q == 0) {
        atomicAdd(&lred[nt * 16 + nl], s);
        atomicAdd(&lred[32 + nt * 16 + nl], s2);
      }
    }
  }
  __syncthreads();
  if (t < 32) {
    int col = c0 + t;
    if (col < DW) atomicAdd(&gs[col], lred[t]);
  } else if (t < 64) {
    int col = c0 + t - 32;
    if (col < DW) atomicAdd(&gs2[col], lred[t]);
  }
}

// ---------------------------------------------------------------------------
// Final concat + dot, with BN2 finalize folded in-block.
// ---------------------------------------------------------------------------
__global__ __launch_bounds__(256) void k_final(const float* __restrict__ lp,
    const float* __restrict__ res, const float* __restrict__ y2,
    const float* __restrict__ gB, const float* __restrict__ gB2,
    const float* __restrict__ g2, const float* __restrict__ bb2,
    const float* __restrict__ ow, const float* __restrict__ ob,
    float* __restrict__ out) {
  __shared__ float lsS[DW], lsH[DW];
  int t = threadIdx.x;
  for (int c = t; c < DW; c += 256) {
    float m = gB[c] * (1.f / BATCH);
    float var = gB2[c] * (1.f / BATCH) - m * m;
    float sc = g2[c] * rsqrtf(var + BN_EPS);
    lsS[c] = sc;
    lsH[c] = bb2[c] - m * sc;
  }
  __syncthreads();
  int lane = t & 63, w = t >> 6;
  int b = blockIdx.x * 4 + w;
  float acc = 0.f;
  for (int j = lane; j < 593; j += 64) {
    float v;
    if (j == 0)       v = lp[b];
    else if (j < 193) v = res[(size_t)b * 192 + (j - 1)];
    else {
      int c = j - 193;
      v = fmaxf(fmaf(y2[(size_t)b * DW + c], lsS[c], lsH[c]), 0.f);
    }
    acc = fmaf(v, ow[j], acc);
  }
#pragma unroll
  for (int k = 1; k < 64; k <<= 1) acc += __shfl_xor(acc, k);
  if (lane == 0) out[b] = acc + ob[0];
}

// ---------------------------------------------------------------------------
extern "C" void kernel_launch(void* const* d_in, const int* in_sizes, int n_in,
                              void* d_out, int out_size, void* d_ws, size_t ws_size,
                              hipStream_t stream) {
  const int*   feat_index = (const int*)d_in[0];
  const float* emb = (const float*)d_in[2];
  const float* lw  = (const float*)d_in[3];
  const float* lb  = (const float*)d_in[4];
  const float* w1  = (const float*)d_in[5];
  const float* b1  = (const float*)d_in[6];
  const float* w2  = (const float*)d_in[7];
  const float* b2  = (const float*)d_in[8];
  const float* dw1 = (const float*)d_in[9];
  const float* db1 = (const float*)d_in[10];
  const float* g1  = (const float*)d_in[11];
  const float* bb1 = (const float*)d_in[12];
  const float* dw2 = (const float*)d_in[13];
  const float* db2 = (const float*)d_in[14];
  const float* g2  = (const float*)d_in[15];
  const float* bb2 = (const float*)d_in[16];
  const float* ow  = (const float*)d_in[17];
  const float* ob  = (const float*)d_in[18];

  float* ws   = (float*)d_ws;
  u16*  flatb = (u16*)ws;                  // 4096*640 bf16 = 1,310,720 f
  float* y1   = ws + 1310720;              // 4096*400 f32
  float* res  = ws + 2949120;              // 4096*192 f32
  float* lp   = ws + 3735552;              // 4096
  float* gA   = ws + 3741248;              // 400 sum
  float* gA2  = gA + 400;
  float* gB   = gA2 + 400;
  float* gB2  = gB + 400;                  // gstat block: 1600 contiguous
  u16*  nxtg  = (u16*)(ws + 3742848);      // 4096*16*64 bf16 = 2,097,152 f
  float* y2   = ws + 3742848;              // alias nxtg (dead after cin2)
  u16*  wp1   = (u16*)(ws + 5840000);      // 327,680 bf16 = 163,840 f
  u16*  wp2   = (u16*)(ws + 6003840);      // 163,840 f
  u16*  wpd1  = (u16*)(ws + 6167680);      // 266,240 bf16 = 133,120 f
  u16*  wpd2  = (u16*)(ws + 6300800);      // 173,056 bf16 -> ends 6,387,328 f
  float* out  = (float*)d_out;

  k_gp<<<BATCH + PREP_B, 256, 0, stream>>>(feat_index, emb, lw, lb, w1, w2,
      dw1, dw2, flatb, lp, wp1, wp2, wpd1, wpd2, gA);
  k_cin_mfma<false><<<dim3(BATCH / 8, 2), 256, 0, stream>>>(
      flatb, nullptr, wp1, b1, nxtg, res);
  k_cin_mfma<true><<<dim3(BATCH / 8, 2), 256, 0, stream>>>(
      flatb, nxtg, wp2, b2, nullptr, res);
  k_gemm_mfma<false, NKS1, IN_DIM, AK1><<<dim3(BATCH / 64, 13), 256, 0, stream>>>(
      flatb, nullptr, wpd1, db1, nullptr, nullptr, nullptr, nullptr, y1, gA, gA2);
  k_gemm_mfma<true, NKS2, DW, 0><<<dim3(BATCH / 64, 13), 256, 0, stream>>>(
      nullptr, y1, wpd2, db2, gA, gA2, g1, bb1, y2, gB, gB2);
  k_final<<<BATCH / 4, 256, 0, stream>>>(lp, res, y2, gB, gB2, g2, bb2, ow, ob, out);
}

// Round 8
// 270.571 us; speedup vs baseline: 1.0613x; 1.0613x over previous
//
#include <hip/hip_runtime.h>

// Problem constants
#define BATCH   4096
#define NF      39          // num_field
#define ED      16          // embedding size
#define IN_DIM  624         // NF*ED
#define DW      400
#define BN_EPS  1e-5f
#define NKSG    78          // CIN K-steps: 39 m * 64 h / 32
#define AK1     640         // padded deep K for layer 1 input (624 -> 640)
#define NKS1    20          // AK1/32
#define NKS2    13          // 400 -> 416 padded
#define WCOL    416         // padded deep-weight column count

typedef __attribute__((ext_vector_type(8))) short short8;
typedef __attribute__((ext_vector_type(4))) float f32x4;
typedef __attribute__((ext_vector_type(2))) float f32x2;
typedef unsigned short u16;

__device__ inline unsigned pack_hi2(float a, float b) {
  // (a>>16) | (b & 0xffff0000) in one v_perm_b32
  return __builtin_amdgcn_perm(__float_as_uint(b), __float_as_uint(a), 0x07060302u);
}
__device__ inline unsigned bf16_rne(float f) {
  unsigned u = __float_as_uint(f);
  u += 0x7fff + ((u >> 16) & 1);
  return u >> 16;
}
__device__ inline float bf2f(u16 v) { return __uint_as_float((unsigned)v << 16); }

#define CIN_E (NKSG * 128 * 32)      // 319488
#define D1_E  (NKS1 * WCOL * 32)     // 266240
#define D2_E  (NKS2 * WCOL * 32)     // 173056
#define PREP_E (CIN_E + D1_E + D2_E + 1600)
#define PREP_B ((PREP_E + 255) / 256)
#define GATH_B (BATCH / 4)

// ---------------------------------------------------------------------------
// Merged: blocks < GATH_B gather embeddings (wave per sample, no barriers);
// rest pack weights into B-fragment layout and zero BN-stat accumulators.
// ---------------------------------------------------------------------------
__global__ __launch_bounds__(256) void k_gp(const int* __restrict__ idx,
    const float* __restrict__ emb, const float* __restrict__ lw,
    const float* __restrict__ lb, const float* __restrict__ w1,
    const float* __restrict__ w2, const float* __restrict__ dw1,
    const float* __restrict__ dw2, u16* __restrict__ flatb,
    float* __restrict__ lp, u16* __restrict__ wp1, u16* __restrict__ wp2,
    u16* __restrict__ wpd1, u16* __restrict__ wpd2, float* __restrict__ gstat) {
  int t = threadIdx.x;
  if (blockIdx.x < GATH_B) {
    int lane = t & 63;
    int b = blockIdx.x * 4 + (t >> 6);
    int sj = (lane < NF) ? idx[b * NF + lane] : 0;
    float acc = 0.f;
#pragma unroll
    for (int i = 0; i < 10; i++) {
      int e = lane + i * 64;
      if (e < IN_DIM) {
        int f = e >> 4;
        int row = __shfl(sj, f);
        float v = emb[(size_t)row * ED + (e & 15)];
        flatb[(size_t)b * AK1 + e] = (u16)bf16_rne(v);
        acc = fmaf(v, lw[e], acc);
      } else {
        flatb[(size_t)b * AK1 + e] = 0;
      }
    }
#pragma unroll
    for (int k = 1; k < 64; k <<= 1) acc += __shfl_xor(acc, k);
    if (lane == 0) lp[b] = acc + lb[0];
  } else {
    int e = (blockIdx.x - GATH_B) * 256 + t;
    if (e < CIN_E) {
      int ksg = e >> 12, r = e & 4095, n = r >> 5, kk = r & 31;
      int k = ksg * 32 + kk, h = k & 63, m = k >> 6;   // m in [0,39)
      float v1 = (h < NF) ? w1[(size_t)n * (NF * NF) + h * NF + m] : 0.f;
      float v2 = w2[(size_t)n * (64 * NF) + h * NF + m];
      wp1[e] = (u16)bf16_rne(v1);
      wp2[e] = (u16)bf16_rne(v2);
    } else if (e < CIN_E + D1_E) {
      int e2 = e - CIN_E;
      int ksg = e2 / (WCOL * 32), r = e2 - ksg * (WCOL * 32);
      int col = r >> 5, kk = r & 31;
      int k = ksg * 32 + kk;
      wpd1[e2] = (k < IN_DIM && col < DW) ? (u16)bf16_rne(dw1[(size_t)k * DW + col]) : 0;
    } else if (e < CIN_E + D1_E + D2_E) {
      int e2 = e - CIN_E - D1_E;
      int ksg = e2 / (WCOL * 32), r = e2 - ksg * (WCOL * 32);
      int col = r >> 5, kk = r & 31;
      int k = ksg * 32 + kk;
      wpd2[e2] = (k < DW && col < DW) ? (u16)bf16_rne(dw2[(size_t)k * DW + col]) : 0;
    } else if (e < PREP_E) {
      gstat[e - CIN_E - D1_E - D2_E] = 0.f;
    }
  }
}

// ---------------------------------------------------------------------------
// CIN via MFMA (r6 grid, register-optimized inner loop).
// Grid (BATCH/16, 2); wave = 4 samples x 4 n-tiles; no LDS, no barriers.
// s1 pre-unpacked to f32 pairs (nxf, 64 VGPR): A-pair = v_pk_mul + v_perm.
// B-fragments prefetched at distance 2 through a 3-slot register ring.
// Reg budget ~210 of 256 -> stays at 2 waves/SIMD (HW cap for this tile).
// ---------------------------------------------------------------------------
template <bool LAY2>
__global__ __launch_bounds__(256, 2) void k_cin_mfma(
    const u16* __restrict__ flatb, const u16* __restrict__ nxtg,
    const u16* __restrict__ wp, const float* __restrict__ bias,
    u16* __restrict__ nxt_out, float* __restrict__ res) {
  int t = threadIdx.x;
  int w = t >> 6, lane = t & 63;
  int nl = lane & 15, q = lane >> 4;
  int d = nl;
  int b0 = blockIdx.x * 16 + w * 4;
  int c0 = blockIdx.y * 64;            // o-half base

  // s1 as f32 pairs: nxf[si][ks][w4] = {s1[h0,d], s1[h1,d]}, h0 = ks*32+q*8+2*w4
  f32x2 nxf[4][2][4];
  if (LAY2) {
#pragma unroll
    for (int si = 0; si < 4; si++)
#pragma unroll
      for (int ks = 0; ks < 2; ks++) {
        uint4 v = *(const uint4*)(nxtg +
            (((size_t)(b0 + si) * 16 + d) * 64 + ks * 32 + q * 8));
        unsigned uu[4] = {v.x, v.y, v.z, v.w};
#pragma unroll
        for (int w4 = 0; w4 < 4; w4++)
          nxf[si][ks][w4] = (f32x2){__uint_as_float(uu[w4] << 16),
                                    __uint_as_float(uu[w4] & 0xffff0000u)};
      }
  } else {
#pragma unroll
    for (int si = 0; si < 4; si++)
#pragma unroll
      for (int ks = 0; ks < 2; ks++)
#pragma unroll
        for (int w4 = 0; w4 < 4; w4++) {
          int h0 = ks * 32 + q * 8 + 2 * w4;
          int h1 = h0 + 1;
          float f0 = (h0 < NF) ? bf2f(flatb[(size_t)(b0 + si) * AK1 + h0 * 16 + d]) : 0.f;
          float f1 = (h1 < NF) ? bf2f(flatb[(size_t)(b0 + si) * AK1 + h1 * 16 + d]) : 0.f;
          nxf[si][ks][w4] = (f32x2){f0, f1};
        }
  }

  f32x4 acc[4][4];
#pragma unroll
  for (int si = 0; si < 4; si++)
#pragma unroll
    for (int nt = 0; nt < 4; nt++) acc[si][nt] = (f32x4){0.f, 0.f, 0.f, 0.f};

  const u16* wbase = wp + (size_t)(c0 + nl) * 32 + q * 8;
  short8 bfr[3][4];
#pragma unroll
  for (int nt = 0; nt < 4; nt++) {
    bfr[0][nt] = *(const short8*)(wbase + nt * 512);            // ksg 0
    bfr[1][nt] = *(const short8*)(wbase + 4096 + nt * 512);     // ksg 1
  }

  float xv[4], xvn[4];
#pragma unroll
  for (int si = 0; si < 4; si++)
    xv[si] = bf2f(flatb[(size_t)(b0 + si) * AK1 + d]);          // m = 0

  for (int mg = 0; mg < 13; mg++) {                             // 13 x 6 = 78 ksg
#pragma unroll
    for (int j = 0; j < 6; j++) {
      int ksg = mg * 6 + j;
      int ks = j & 1;
      // prefetch B at distance 2 into ring slot (j+2)%3
      if (j < 4 || mg < 12) {
        const u16* wb = wbase + (size_t)(ksg + 2) * 4096;
#pragma unroll
        for (int nt = 0; nt < 4; nt++)
          bfr[(j + 2) % 3][nt] = *(const short8*)(wb + nt * 512);
      }
      if (ks == 0) {
        int m = ksg >> 1;
        // prefetch x for m+1 (row 39 = zero padding, safe)
#pragma unroll
        for (int si = 0; si < 4; si++)
          xvn[si] = bf2f(flatb[(size_t)(b0 + si) * AK1 + (m + 1) * 16 + d]);
      }
      short8 afr[4];
#pragma unroll
      for (int si = 0; si < 4; si++) {
        union { unsigned u[4]; short8 s; } a;
        f32x2 xv2 = (f32x2){xv[si], xv[si]};
#pragma unroll
        for (int w4 = 0; w4 < 4; w4++) {
          f32x2 p = nxf[si][ks][w4] * xv2;      // v_pk_mul_f32
          a.u[w4] = pack_hi2(p[0], p[1]);       // v_perm_b32
        }
        afr[si] = a.s;
      }
#pragma unroll
      for (int nt = 0; nt < 4; nt++)
#pragma unroll
        for (int si = 0; si < 4; si++)
          acc[si][nt] = __builtin_amdgcn_mfma_f32_16x16x32_bf16(
              afr[si], bfr[j % 3][nt], acc[si][nt], 0, 0, 0);
      if (ks == 1) {
#pragma unroll
        for (int si = 0; si < 4; si++) xv[si] = xvn[si];
      }
    }
  }

  // Epilogue. C layout: col = nl (within n-tile), row d' = q*4 + r.
#pragma unroll
  for (int si = 0; si < 4; si++) {
    int b = b0 + si;
#pragma unroll
    for (int nt = 0; nt < 4; nt++) {
      int o = c0 + nt * 16 + nl;
      float bi = bias[o];
      if (!LAY2 && c0 == 0) {
#pragma unroll
        for (int r = 0; r < 4; r++) {
          float v = fmaxf(acc[si][nt][r] + bi, 0.f);
          nxt_out[((size_t)b * 16 + q * 4 + r) * 64 + o] = (u16)bf16_rne(v);
        }
      } else {
        float s = 0.f;
#pragma unroll
        for (int r = 0; r < 4; r++) s += fmaxf(acc[si][nt][r] + bi, 0.f);
        s += __shfl_xor(s, 16);
        s += __shfl_xor(s, 32);
        if (q == 0) {
          int ri = LAY2 ? (64 + o) : (o - 64);
          res[(size_t)b * 192 + ri] = s;
        }
      }
    }
  }
}

// ---------------------------------------------------------------------------
// Deep-tower GEMM via MFMA. Grid (M/64, 13), wave = 16 rows x 32 cols
// (2 n-tiles). Weights padded to 416 cols. BN_A folds previous layer's BN
// finalize in-block and applies BN+ReLU to A. Fused BN stats -> atomics.
// ---------------------------------------------------------------------------
template <bool BN_A, int NKS, int KREAL, int AK>
__global__ __launch_bounds__(256) void k_gemm_mfma(
    const u16* __restrict__ Abf, const float* __restrict__ Af32,
    const u16* __restrict__ wp, const float* __restrict__ bias,
    const float* __restrict__ gsIn, const float* __restrict__ gs2In,
    const float* __restrict__ bng, const float* __restrict__ bnb,
    float* __restrict__ C, float* __restrict__ gs, float* __restrict__ gs2) {
  __shared__ float lsS[NKS * 32], lsH[NKS * 32];
  __shared__ float lred[64];
  int t = threadIdx.x;
  if (BN_A) {
    for (int c = t; c < NKS * 32; c += 256) {
      float sc = 0.f, sh = 0.f;
      if (c < DW) {
        float m = gsIn[c] * (1.f / BATCH);
        float var = gs2In[c] * (1.f / BATCH) - m * m;
        sc = bng[c] * rsqrtf(var + BN_EPS);
        sh = bnb[c] - m * sc;
      }
      lsS[c] = sc; lsH[c] = sh;
    }
  }
  if (t < 64) lred[t] = 0.f;
  __syncthreads();

  int w = t >> 6, lane = t & 63;
  int nl = lane & 15, q = lane >> 4;
  int row = blockIdx.x * 64 + w * 16 + nl;
  int c0 = blockIdx.y * 32;
  f32x4 acc[2];
  acc[0] = (f32x4){0.f, 0.f, 0.f, 0.f};
  acc[1] = (f32x4){0.f, 0.f, 0.f, 0.f};

  short8 araw[2]; f32x4 fraw0[2], fraw1[2]; short8 braw[2][2];
  auto loadA_raw = [&](int ksg, int buf) {
    int kb = ksg * 32 + q * 8;
    if (!BN_A) {
      araw[buf] = *(const short8*)(Abf + (size_t)row * AK + kb);
    } else {
      if (kb + 8 <= KREAL) {
        fraw0[buf] = *(const f32x4*)(Af32 + (size_t)row * KREAL + kb);
        fraw1[buf] = *(const f32x4*)(Af32 + (size_t)row * KREAL + kb + 4);
      } else {
        fraw0[buf] = (f32x4){0.f,0.f,0.f,0.f};
        fraw1[buf] = (f32x4){0.f,0.f,0.f,0.f};
      }
    }
    const u16* wb = wp + (size_t)ksg * (WCOL * 32) + (size_t)(c0 + nl) * 32 + q * 8;
    braw[buf][0] = *(const short8*)wb;
    braw[buf][1] = *(const short8*)(wb + 16 * 32);
  };
  auto cookA = [&](int ksg, int buf) -> short8 {
    if (!BN_A) return araw[buf];
    int kb = ksg * 32 + q * 8;
    f32x4 s0 = *(const f32x4*)&lsS[kb], h0 = *(const f32x4*)&lsH[kb];
    f32x4 s1 = *(const f32x4*)&lsS[kb + 4], h1 = *(const f32x4*)&lsH[kb + 4];
    union { unsigned u[4]; short8 s; } a;
    float v0 = fmaxf(fmaf(fraw0[buf][0], s0[0], h0[0]), 0.f);
    float v1 = fmaxf(fmaf(fraw0[buf][1], s0[1], h0[1]), 0.f);
    float v2 = fmaxf(fmaf(fraw0[buf][2], s0[2], h0[2]), 0.f);
    float v3 = fmaxf(fmaf(fraw0[buf][3], s0[3], h0[3]), 0.f);
    float v4 = fmaxf(fmaf(fraw1[buf][0], s1[0], h1[0]), 0.f);
    float v5 = fmaxf(fmaf(fraw1[buf][1], s1[1], h1[1]), 0.f);
    float v6 = fmaxf(fmaf(fraw1[buf][2], s1[2], h1[2]), 0.f);
    float v7 = fmaxf(fmaf(fraw1[buf][3], s1[3], h1[3]), 0.f);
    a.u[0] = bf16_rne(v0) | (bf16_rne(v1) << 16);
    a.u[1] = bf16_rne(v2) | (bf16_rne(v3) << 16);
    a.u[2] = bf16_rne(v4) | (bf16_rne(v5) << 16);
    a.u[3] = bf16_rne(v6) | (bf16_rne(v7) << 16);
    return a.s;
  };

  loadA_raw(0, 0);
#pragma unroll 4
  for (int ksg = 0; ksg < NKS; ksg++) {
    int cur = ksg & 1;
    if (ksg + 1 < NKS) loadA_raw(ksg + 1, cur ^ 1);
    short8 afr = cookA(ksg, cur);
    acc[0] = __builtin_amdgcn_mfma_f32_16x16x32_bf16(afr, braw[cur][0], acc[0], 0, 0, 0);
    acc[1] = __builtin_amdgcn_mfma_f32_16x16x32_bf16(afr, braw[cur][1], acc[1], 0, 0, 0);
  }

  int rbase = blockIdx.x * 64 + w * 16 + q * 4;
#pragma unroll
  for (int nt = 0; nt < 2; nt++) {
    int col = c0 + nt * 16 + nl;
    if (col < DW) {
      float bi = bias[col];
      float s = 0.f, s2 = 0.f;
#pragma unroll
      for (int r = 0; r < 4; r++) {
        float v = acc[nt][r] + bi;
        C[(size_t)(rbase + r) * DW + col] = v;
        s += v; s2 = fmaf(v, v, s2);
      }
      s += __shfl_xor(s, 16); s2 += __shfl_xor(s2, 16);
      s += __shfl_xor(s, 32); s2 += __shfl_xor(s2, 32);
      if (q == 0) {
        atomicAdd(&lred[nt * 16 + nl], s);
        atomicAdd(&lred[32 + nt * 16 + nl], s2);
      }
    }
  }
  __syncthreads();
  if (t < 32) {
    int col = c0 + t;
    if (col < DW) atomicAdd(&gs[col], lred[t]);
  } else if (t < 64) {
    int col = c0 + t - 32;
    if (col < DW) atomicAdd(&gs2[col], lred[t]);
  }
}

// ---------------------------------------------------------------------------
// Final concat + dot, with BN2 finalize folded in-block.
// ---------------------------------------------------------------------------
__global__ __launch_bounds__(256) void k_final(const float* __restrict__ lp,
    const float* __restrict__ res, const float* __restrict__ y2,
    const float* __restrict__ gB, const float* __restrict__ gB2,
    const float* __restrict__ g2, const float* __restrict__ bb2,
    const float* __restrict__ ow, const float* __restrict__ ob,
    float* __restrict__ out) {
  __shared__ float lsS[DW], lsH[DW];
  int t = threadIdx.x;
  for (int c = t; c < DW; c += 256) {
    float m = gB[c] * (1.f / BATCH);
    float var = gB2[c] * (1.f / BATCH) - m * m;
    float sc = g2[c] * rsqrtf(var + BN_EPS);
    lsS[c] = sc;
    lsH[c] = bb2[c] - m * sc;
  }
  __syncthreads();
  int lane = t & 63, w = t >> 6;
  int b = blockIdx.x * 4 + w;
  float acc = 0.f;
  for (int j = lane; j < 593; j += 64) {
    float v;
    if (j == 0)       v = lp[b];
    else if (j < 193) v = res[(size_t)b * 192 + (j - 1)];
    else {
      int c = j - 193;
      v = fmaxf(fmaf(y2[(size_t)b * DW + c], lsS[c], lsH[c]), 0.f);
    }
    acc = fmaf(v, ow[j], acc);
  }
#pragma unroll
  for (int k = 1; k < 64; k <<= 1) acc += __shfl_xor(acc, k);
  if (lane == 0) out[b] = acc + ob[0];
}

// ---------------------------------------------------------------------------
extern "C" void kernel_launch(void* const* d_in, const int* in_sizes, int n_in,
                              void* d_out, int out_size, void* d_ws, size_t ws_size,
                              hipStream_t stream) {
  const int*   feat_index = (const int*)d_in[0];
  const float* emb = (const float*)d_in[2];
  const float* lw  = (const float*)d_in[3];
  const float* lb  = (const float*)d_in[4];
  const float* w1  = (const float*)d_in[5];
  const float* b1  = (const float*)d_in[6];
  const float* w2  = (const float*)d_in[7];
  const float* b2  = (const float*)d_in[8];
  const float* dw1 = (const float*)d_in[9];
  const float* db1 = (const float*)d_in[10];
  const float* g1  = (const float*)d_in[11];
  const float* bb1 = (const float*)d_in[12];
  const float* dw2 = (const float*)d_in[13];
  const float* db2 = (const float*)d_in[14];
  const float* g2  = (const float*)d_in[15];
  const float* bb2 = (const float*)d_in[16];
  const float* ow  = (const float*)d_in[17];
  const float* ob  = (const float*)d_in[18];

  float* ws   = (float*)d_ws;
  u16*  flatb = (u16*)ws;                  // 4096*640 bf16 = 1,310,720 f
  float* y1   = ws + 1310720;              // 4096*400 f32
  float* res  = ws + 2949120;              // 4096*192 f32
  float* lp   = ws + 3735552;              // 4096
  float* gA   = ws + 3741248;              // 400 sum
  float* gA2  = gA + 400;
  float* gB   = gA2 + 400;
  float* gB2  = gB + 400;                  // gstat block: 1600 contiguous
  u16*  nxtg  = (u16*)(ws + 3742848);      // 4096*16*64 bf16 = 2,097,152 f
  float* y2   = ws + 3742848;              // alias nxtg (dead after cin2)
  u16*  wp1   = (u16*)(ws + 5840000);      // 319,488 bf16
  u16*  wp2   = (u16*)(ws + 6003840);
  u16*  wpd1  = (u16*)(ws + 6167680);      // 266,240 bf16
  u16*  wpd2  = (u16*)(ws + 6300800);      // 173,056 bf16
  float* out  = (float*)d_out;

  k_gp<<<GATH_B + PREP_B, 256, 0, stream>>>(feat_index, emb, lw, lb, w1, w2,
      dw1, dw2, flatb, lp, wp1, wp2, wpd1, wpd2, gA);
  k_cin_mfma<false><<<dim3(BATCH / 16, 2), 256, 0, stream>>>(
      flatb, nullptr, wp1, b1, nxtg, res);
  k_cin_mfma<true><<<dim3(BATCH / 16, 2), 256, 0, stream>>>(
      flatb, nxtg, wp2, b2, nullptr, res);
  k_gemm_mfma<false, NKS1, IN_DIM, AK1><<<dim3(BATCH / 64, 13), 256, 0, stream>>>(
      flatb, nullptr, wpd1, db1, nullptr, nullptr, nullptr, nullptr, y1, gA, gA2);
  k_gemm_mfma<true, NKS2, DW, 0><<<dim3(BATCH / 64, 13), 256, 0, stream>>>(
      nullptr, y1, wpd2, db2, gA, gA2, g1, bb1, y2, gB, gB2);
  k_final<<<BATCH / 4, 256, 0, stream>>>(lp, res, y2, gB, gB2, g2, bb2, ow, ob, out);
}